// Round 1
// baseline (52.462 us; speedup 1.0000x reference)
//
#include <hip/hip_runtime.h>
#include <math.h>

#define NN 1024
#define DD 64
#define HH 256
#define TEMP_INV 10.0f
#define TI 32
#define TJ 128
#define KC 64
#define NJC (NN / TJ)   // 8 j-chunks

// ws layout (floats):
//   xpbT [HH][NN]   : xp + b1, transposed (k-major)
//   ypT  [HH][NN]   : yp, transposed
//   pos  [NN]
//   pmax [NN][NJC]
//   psum [NN][NJC]
// total = 2*256*1024 + 1024 + 2*1024*8 floats ~= 2.1 MB

__global__ __launch_bounds__(256)
void k1_proj(const float* __restrict__ x, const float* __restrict__ y,
             const float* __restrict__ W1, const float* __restrict__ b1,
             const float* __restrict__ w2, const float* __restrict__ b2,
             float* __restrict__ xpbT, float* __restrict__ ypT,
             float* __restrict__ pos)
{
    __shared__ float xls[4][DD];
    __shared__ float yls[4][DD];
    __shared__ float4 red[256];
    const int tid = threadIdx.x;
    const int i0 = blockIdx.x * 4;

    for (int idx = tid; idx < 4 * DD; idx += 256) {
        int r = idx >> 6, c = idx & 63;
        xls[r][c] = x[(i0 + r) * DD + c];
        yls[r][c] = y[(i0 + r) * DD + c];
    }
    __syncthreads();

    float ax[4] = {0.f, 0.f, 0.f, 0.f};
    float ay[4] = {0.f, 0.f, 0.f, 0.f};
    #pragma unroll 8
    for (int kk = 0; kk < DD; ++kk) {
        const float wx = W1[kk * HH + tid];          // W1x row kk, col tid
        const float wy = W1[(DD + kk) * HH + tid];   // W1y row kk, col tid
        #pragma unroll
        for (int r = 0; r < 4; ++r) {
            ax[r] = fmaf(xls[r][kk], wx, ax[r]);
            ay[r] = fmaf(yls[r][kk], wy, ay[r]);
        }
    }

    const float b1t = b1[tid];
    const float w2t = w2[tid];
    float xb[4];
    #pragma unroll
    for (int r = 0; r < 4; ++r) xb[r] = ax[r] + b1t;

    // transposed stores: row k = tid, cols i0..i0+3 (16B aligned)
    *(float4*)&xpbT[tid * NN + i0] = make_float4(xb[0], xb[1], xb[2], xb[3]);
    *(float4*)&ypT[tid * NN + i0]  = make_float4(ay[0], ay[1], ay[2], ay[3]);

    float4 pr;
    pr.x = fmaxf(xb[0] + ay[0], 0.f) * w2t;
    pr.y = fmaxf(xb[1] + ay[1], 0.f) * w2t;
    pr.z = fmaxf(xb[2] + ay[2], 0.f) * w2t;
    pr.w = fmaxf(xb[3] + ay[3], 0.f) * w2t;
    red[tid] = pr;
    __syncthreads();
    for (int s = 128; s > 0; s >>= 1) {
        if (tid < s) {
            float4 o = red[tid + s], m = red[tid];
            m.x += o.x; m.y += o.y; m.z += o.z; m.w += o.w;
            red[tid] = m;
        }
        __syncthreads();
    }
    if (tid == 0) {
        const float bb = b2[0];
        pos[i0 + 0] = (red[0].x + bb) * TEMP_INV;
        pos[i0 + 1] = (red[0].y + bb) * TEMP_INV;
        pos[i0 + 2] = (red[0].z + bb) * TEMP_INV;
        pos[i0 + 3] = (red[0].w + bb) * TEMP_INV;
    }
}

__global__ __launch_bounds__(256)
void k2_scores(const float* __restrict__ xpbT, const float* __restrict__ ypT,
               const float* __restrict__ w2, const float* __restrict__ b2,
               float* __restrict__ pmax, float* __restrict__ psum)
{
    __shared__ float ys[KC][TI];    // 8 KB
    __shared__ float xs[KC][TJ];    // 32 KB
    __shared__ float w2s[HH];       // 1 KB
    const int tid = threadIdx.x;
    const int bj = blockIdx.x;      // 0..7
    const int bi = blockIdx.y;      // 0..31
    const int i0 = bi * TI, j0 = bj * TJ;

    w2s[tid] = w2[tid];

    const int a = tid >> 5;   // 0..7: owns rows i0 + 4a .. +3
    const int b = tid & 31;   // 0..31: owns cols j0 + 4b .. +3

    float acc[4][4];
    #pragma unroll
    for (int p = 0; p < 4; ++p)
        #pragma unroll
        for (int q = 0; q < 4; ++q) acc[p][q] = 0.f;

    for (int kc = 0; kc < HH; kc += KC) {
        __syncthreads();   // protect LDS from previous chunk's readers (and w2s on iter 0)
        #pragma unroll
        for (int g = 0; g < 8; ++g) {
            const int kk = a + g * 8;
            ys[kk][b] = ypT[(kc + kk) * NN + i0 + b];
            *(float4*)&xs[kk][b * 4] =
                *(const float4*)&xpbT[(kc + kk) * NN + j0 + b * 4];
        }
        __syncthreads();
        #pragma unroll 8
        for (int kk = 0; kk < KC; ++kk) {
            const float w2k = w2s[kc + kk];
            const float4 yv4 = *(const float4*)&ys[kk][a * 4];
            const float4 xv4 = *(const float4*)&xs[kk][b * 4];
            const float yv[4] = {yv4.x, yv4.y, yv4.z, yv4.w};
            const float xv[4] = {xv4.x, xv4.y, xv4.z, xv4.w};
            #pragma unroll
            for (int p = 0; p < 4; ++p)
                #pragma unroll
                for (int q = 0; q < 4; ++q)
                    acc[p][q] = fmaf(fmaxf(yv[p] + xv[q], 0.f), w2k, acc[p][q]);
        }
    }

    // epilogue: per-row (over this j-chunk) max & sum(exp), half-wave reduce over b
    const float bb = b2[0];
    #pragma unroll
    for (int p = 0; p < 4; ++p) {
        float s0 = (acc[p][0] + bb) * TEMP_INV;
        float s1 = (acc[p][1] + bb) * TEMP_INV;
        float s2 = (acc[p][2] + bb) * TEMP_INV;
        float s3 = (acc[p][3] + bb) * TEMP_INV;
        float m = fmaxf(fmaxf(s0, s1), fmaxf(s2, s3));
        #pragma unroll
        for (int mk = 16; mk >= 1; mk >>= 1) m = fmaxf(m, __shfl_xor(m, mk));
        float e = expf(s0 - m) + expf(s1 - m) + expf(s2 - m) + expf(s3 - m);
        #pragma unroll
        for (int mk = 16; mk >= 1; mk >>= 1) e += __shfl_xor(e, mk);
        if (b == 0) {
            const int row = i0 + a * 4 + p;
            pmax[row * NJC + bj] = m;
            psum[row * NJC + bj] = e;
        }
    }
}

__global__ __launch_bounds__(256)
void k3_final(const float* __restrict__ pmax, const float* __restrict__ psum,
              const float* __restrict__ pos, float* __restrict__ out)
{
    __shared__ float2 red[256];
    const int tid = threadIdx.x;
    float lacc = 0.f, pacc = 0.f;
    #pragma unroll
    for (int r = 0; r < 4; ++r) {
        const int row = tid * 4 + r;
        float M = -1e30f;
        #pragma unroll
        for (int c = 0; c < NJC; ++c) M = fmaxf(M, pmax[row * NJC + c]);
        float S = 0.f;
        #pragma unroll
        for (int c = 0; c < NJC; ++c)
            S += psum[row * NJC + c] * expf(pmax[row * NJC + c] - M);
        lacc += M + logf(S);
        pacc += pos[row];
    }
    red[tid] = make_float2(lacc, pacc);
    __syncthreads();
    for (int s = 128; s > 0; s >>= 1) {
        if (tid < s) {
            float2 o = red[tid + s], m2 = red[tid];
            m2.x += o.x; m2.y += o.y;
            red[tid] = m2;
        }
        __syncthreads();
    }
    if (tid == 0) {
        // loss = lse.mean() - log(n) - pos.mean()
        out[0] = red[0].x / (float)NN - logf((float)NN) - red[0].y / (float)NN;
    }
}

extern "C" void kernel_launch(void* const* d_in, const int* in_sizes, int n_in,
                              void* d_out, int out_size, void* d_ws, size_t ws_size,
                              hipStream_t stream)
{
    const float* x  = (const float*)d_in[0];
    const float* y  = (const float*)d_in[1];
    const float* W1 = (const float*)d_in[2];
    const float* b1 = (const float*)d_in[3];
    const float* w2 = (const float*)d_in[4];
    const float* b2 = (const float*)d_in[5];
    float* out = (float*)d_out;

    float* ws   = (float*)d_ws;
    float* xpbT = ws;                 // 256*1024
    float* ypT  = xpbT + HH * NN;     // 256*1024
    float* pos  = ypT + HH * NN;      // 1024
    float* pmax = pos + NN;           // 1024*8
    float* psum = pmax + NN * NJC;    // 1024*8

    hipLaunchKernelGGL(k1_proj, dim3(NN / 4), dim3(256), 0, stream,
                       x, y, W1, b1, w2, b2, xpbT, ypT, pos);
    hipLaunchKernelGGL(k2_scores, dim3(NJC, NN / TI), dim3(256), 0, stream,
                       xpbT, ypT, w2, b2, pmax, psum);
    hipLaunchKernelGGL(k3_final, dim3(1), dim3(256), 0, stream,
                       pmax, psum, pos, out);
}

// Round 2
// 51.177 us; speedup vs baseline: 1.0251x; 1.0251x over previous
//
#include <hip/hip_runtime.h>
#include <math.h>

#define NN 1024
#define DD 64
#define HH 256
#define TEMP_INV 10.0f
#define NJC 32          // 32 col-chunks of 32 cols each

// ws layout (floats):
//   xpbT [HH][NN] : xp + b1, transposed (k-major)
//   ypT  [HH][NN] : yp, transposed
//   pos  [NN]
//   pmax [NJC][NN]
//   psum [NJC][NN]

__global__ __launch_bounds__(256)
void k1_proj(const float* __restrict__ x, const float* __restrict__ y,
             const float* __restrict__ W1, const float* __restrict__ b1,
             float* __restrict__ xpbT, float* __restrict__ ypT)
{
    const int tid = threadIdx.x;        // h index 0..255
    const int i0 = blockIdx.x * 4;      // 4 rows per block

    float ax[4] = {0.f, 0.f, 0.f, 0.f};
    float ay[4] = {0.f, 0.f, 0.f, 0.f};
    #pragma unroll 8
    for (int kk = 0; kk < DD; ++kk) {
        const float wx = W1[kk * HH + tid];         // W1x col tid (vector, coalesced)
        const float wy = W1[(DD + kk) * HH + tid];  // W1y col tid
        #pragma unroll
        for (int r = 0; r < 4; ++r) {
            // x/y operands are wave-uniform -> scalar loads
            ax[r] = fmaf(x[(i0 + r) * DD + kk], wx, ax[r]);
            ay[r] = fmaf(y[(i0 + r) * DD + kk], wy, ay[r]);
        }
    }
    const float b1t = b1[tid];
    *(float4*)&xpbT[tid * NN + i0] =
        make_float4(ax[0] + b1t, ax[1] + b1t, ax[2] + b1t, ax[3] + b1t);
    *(float4*)&ypT[tid * NN + i0] = make_float4(ay[0], ay[1], ay[2], ay[3]);
}

// Each lane owns one row (y, vector load); each wave owns 8 uniform cols
// (x + w2 via scalar loads). No LDS, no barriers in the K loop.
__global__ __launch_bounds__(256)
void k2_scores(const float* __restrict__ xpbT, const float* __restrict__ ypT,
               const float* __restrict__ w2, const float* __restrict__ b2,
               float* __restrict__ pmax, float* __restrict__ psum,
               float* __restrict__ pos)
{
    __shared__ float lm[4][64];
    __shared__ float le[4][64];
    const int tid  = threadIdx.x;
    const int lane = tid & 63;
    const int w    = __builtin_amdgcn_readfirstlane(tid >> 6);  // wave id, uniform
    const int bj   = blockIdx.x;            // 0..31 : col-chunk of 32
    const int bi   = blockIdx.y;            // 0..15 : row-chunk of 64
    const int rg   = bi * 64 + lane;        // global row (per-lane)
    const int c0   = bj * 32 + w * 8;       // uniform col base, 8 cols per wave

    const float* ycol = ypT + rg;           // + kk*NN (per-lane, coalesced)
    const float* xrow = xpbT + c0;          // + kk*NN (wave-uniform -> s_load)

    float acc[8];
    #pragma unroll
    for (int q = 0; q < 8; ++q) acc[q] = 0.f;

    #pragma unroll 4
    for (int kk = 0; kk < HH; ++kk) {
        const float yv  = ycol[kk * NN];
        const float w2k = w2[kk];           // uniform -> s_load
        #pragma unroll
        for (int q = 0; q < 8; ++q)
            acc[q] = fmaf(fmaxf(yv + xrow[kk * NN + q], 0.f), w2k, acc[q]);
    }

    const float bb = b2[0];
    float s[8];
    #pragma unroll
    for (int q = 0; q < 8; ++q) s[q] = (acc[q] + bb) * TEMP_INV;

    // diagonal element = pos[rg]
    const int dq = rg - c0;
    if (dq >= 0 && dq < 8) {
        #pragma unroll
        for (int q = 0; q < 8; ++q)
            if (q == dq) pos[rg] = s[q];
    }

    // per-lane (per-row) partial over this wave's 8 cols
    float m = s[0];
    #pragma unroll
    for (int q = 1; q < 8; ++q) m = fmaxf(m, s[q]);
    float e = 0.f;
    #pragma unroll
    for (int q = 0; q < 8; ++q) e += __expf(s[q] - m);

    lm[w][lane] = m;
    le[w][lane] = e;
    __syncthreads();
    if (w == 0) {
        float M = lm[0][lane];
        #pragma unroll
        for (int u = 1; u < 4; ++u) M = fmaxf(M, lm[u][lane]);
        float E = 0.f;
        #pragma unroll
        for (int u = 0; u < 4; ++u) E += le[u][lane] * __expf(lm[u][lane] - M);
        pmax[bj * NN + rg] = M;   // coalesced over lanes
        psum[bj * NN + rg] = E;
    }
}

__global__ __launch_bounds__(256)
void k3_final(const float* __restrict__ pmax, const float* __restrict__ psum,
              const float* __restrict__ pos, float* __restrict__ out)
{
    __shared__ float2 red[256];
    const int tid = threadIdx.x;
    float lacc = 0.f, pacc = 0.f;
    #pragma unroll
    for (int r = 0; r < 4; ++r) {
        const int row = tid + r * 256;      // coalesced over tid
        float M = pmax[row];
        #pragma unroll
        for (int c = 1; c < NJC; ++c) M = fmaxf(M, pmax[c * NN + row]);
        float S = 0.f;
        #pragma unroll
        for (int c = 0; c < NJC; ++c)
            S += psum[c * NN + row] * __expf(pmax[c * NN + row] - M);
        lacc += M + logf(S);
        pacc += pos[row];
    }
    red[tid] = make_float2(lacc, pacc);
    __syncthreads();
    for (int s = 128; s > 0; s >>= 1) {
        if (tid < s) {
            float2 o = red[tid + s], m2 = red[tid];
            m2.x += o.x; m2.y += o.y;
            red[tid] = m2;
        }
        __syncthreads();
    }
    if (tid == 0) {
        out[0] = red[0].x / (float)NN - logf((float)NN) - red[0].y / (float)NN;
    }
}

extern "C" void kernel_launch(void* const* d_in, const int* in_sizes, int n_in,
                              void* d_out, int out_size, void* d_ws, size_t ws_size,
                              hipStream_t stream)
{
    const float* x  = (const float*)d_in[0];
    const float* y  = (const float*)d_in[1];
    const float* W1 = (const float*)d_in[2];
    const float* b1 = (const float*)d_in[3];
    const float* w2 = (const float*)d_in[4];
    const float* b2 = (const float*)d_in[5];
    float* out = (float*)d_out;

    float* ws   = (float*)d_ws;
    float* xpbT = ws;                  // 256*1024
    float* ypT  = xpbT + HH * NN;      // 256*1024
    float* pos  = ypT + HH * NN;       // 1024
    float* pmax = pos + NN;            // 32*1024
    float* psum = pmax + NJC * NN;     // 32*1024

    hipLaunchKernelGGL(k1_proj, dim3(NN / 4), dim3(256), 0, stream,
                       x, y, W1, b1, xpbT, ypT);
    hipLaunchKernelGGL(k2_scores, dim3(NJC, NN / 64), dim3(256), 0, stream,
                       xpbT, ypT, w2, b2, pmax, psum, pos);
    hipLaunchKernelGGL(k3_final, dim3(1), dim3(256), 0, stream,
                       pmax, psum, pos, out);
}

// Round 3
// 48.366 us; speedup vs baseline: 1.0847x; 1.0581x over previous
//
#include <hip/hip_runtime.h>
#include <math.h>

#define NN 1024
#define DD 64
#define HH 256
#define TEMP_INV 10.0f
#define KCH 64
#define NKC 4

// ws layout (floats):
//   xpbT   [HH][NN]      : xp + b1, transposed (k-major)   1 MB
//   ypT    [HH][NN]      : yp, transposed                  1 MB
//   pscore [NKC][NN][NN] : partial scores per k-chunk     16 MB
//   lse    [NN]
//   pos    [NN]

__global__ __launch_bounds__(256)
void k1_proj(const float* __restrict__ x, const float* __restrict__ y,
             const float* __restrict__ W1, const float* __restrict__ b1,
             float* __restrict__ xpbT, float* __restrict__ ypT)
{
    const int tid = threadIdx.x;        // h index 0..255
    const int i0 = blockIdx.x * 2;      // 2 rows per block -> 512 blocks
    float ax[2] = {0.f, 0.f}, ay[2] = {0.f, 0.f};
    #pragma unroll 8
    for (int kk = 0; kk < DD; ++kk) {
        const float wx = W1[kk * HH + tid];
        const float wy = W1[(DD + kk) * HH + tid];
        #pragma unroll
        for (int r = 0; r < 2; ++r) {
            ax[r] = fmaf(x[(i0 + r) * DD + kk], wx, ax[r]);
            ay[r] = fmaf(y[(i0 + r) * DD + kk], wy, ay[r]);
        }
    }
    const float b1t = b1[tid];
    *(float2*)&xpbT[tid * NN + i0] = make_float2(ax[0] + b1t, ax[1] + b1t);
    *(float2*)&ypT[tid * NN + i0]  = make_float2(ay[0], ay[1]);
}

// 64x64 output tile, 64-k chunk per block. 4x4 register tile per thread.
// Grid (16 j, 16 i, 4 k) = 1024 blocks = 4096 waves = 4 waves/SIMD.
__global__ __launch_bounds__(256)
void k2_scores(const float* __restrict__ xpbT, const float* __restrict__ ypT,
               const float* __restrict__ w2,
               float* __restrict__ pscore)
{
    __shared__ float ys[KCH][64];   // 16 KB
    __shared__ float xs[KCH][64];   // 16 KB
    const int tid = threadIdx.x;
    const int bj = blockIdx.x, bi = blockIdx.y, bk = blockIdx.z;
    const int i0 = bi * 64, j0 = bj * 64, k0 = bk * KCH;
    const int lr = tid >> 4;    // 0..15
    const int lc = tid & 15;    // 0..15

    #pragma unroll
    for (int g = 0; g < 4; ++g) {
        const int kk = lr + g * 16;
        *(float4*)&ys[kk][lc * 4] = *(const float4*)&ypT[(k0 + kk) * NN + i0 + lc * 4];
        *(float4*)&xs[kk][lc * 4] = *(const float4*)&xpbT[(k0 + kk) * NN + j0 + lc * 4];
    }
    __syncthreads();

    float acc[4][4];
    #pragma unroll
    for (int p = 0; p < 4; ++p)
        #pragma unroll
        for (int q = 0; q < 4; ++q) acc[p][q] = 0.f;

    #pragma unroll 8
    for (int kk = 0; kk < KCH; ++kk) {
        const float w2k = w2[k0 + kk];               // uniform -> scalar load
        const float4 yv4 = *(const float4*)&ys[kk][lr * 4];
        const float4 xv4 = *(const float4*)&xs[kk][lc * 4];
        const float yv[4] = {yv4.x, yv4.y, yv4.z, yv4.w};
        const float xv[4] = {xv4.x, xv4.y, xv4.z, xv4.w};
        #pragma unroll
        for (int p = 0; p < 4; ++p)
            #pragma unroll
            for (int q = 0; q < 4; ++q)
                acc[p][q] = fmaf(fmaxf(yv[p] + xv[q], 0.f), w2k, acc[p][q]);
    }

    float* dst = pscore + (size_t)bk * NN * NN;
    #pragma unroll
    for (int p = 0; p < 4; ++p)
        *(float4*)&dst[(i0 + lr * 4 + p) * NN + j0 + lc * 4] =
            make_float4(acc[p][0], acc[p][1], acc[p][2], acc[p][3]);
}

// Per-row LSE over summed partials. 128 blocks x 256 thr; 32 lanes per row.
__global__ __launch_bounds__(256)
void k3_lse(const float* __restrict__ pscore, const float* __restrict__ b2,
            float* __restrict__ lse, float* __restrict__ pos)
{
    const int tid  = threadIdx.x;
    const int row  = blockIdx.x * 8 + (tid >> 5);
    const int tcol = tid & 31;
    const float bb = b2[0];
    const float* P0 = pscore;
    const float* P1 = pscore + (size_t)1 * NN * NN;
    const float* P2 = pscore + (size_t)2 * NN * NN;
    const float* P3 = pscore + (size_t)3 * NN * NN;
    const size_t rbase = (size_t)row * NN;

    float M = -1e30f, S = 0.f;
    #pragma unroll
    for (int m = 0; m < 8; ++m) {
        const int col = m * 128 + tcol * 4;
        const float4 a0 = *(const float4*)&P0[rbase + col];
        const float4 a1 = *(const float4*)&P1[rbase + col];
        const float4 a2 = *(const float4*)&P2[rbase + col];
        const float4 a3 = *(const float4*)&P3[rbase + col];
        float s[4];
        s[0] = (a0.x + a1.x + a2.x + a3.x + bb) * TEMP_INV;
        s[1] = (a0.y + a1.y + a2.y + a3.y + bb) * TEMP_INV;
        s[2] = (a0.z + a1.z + a2.z + a3.z + bb) * TEMP_INV;
        s[3] = (a0.w + a1.w + a2.w + a3.w + bb) * TEMP_INV;
        if (row >= col && row < col + 4)
            pos[row] = s[row - col];
        const float m4 = fmaxf(fmaxf(s[0], s[1]), fmaxf(s[2], s[3]));
        if (m4 > M) { S *= __expf(M - m4); M = m4; }
        S += __expf(s[0] - M) + __expf(s[1] - M) +
             __expf(s[2] - M) + __expf(s[3] - M);
    }
    #pragma unroll
    for (int mk = 16; mk >= 1; mk >>= 1) {
        const float Mo = __shfl_xor(M, mk);
        const float So = __shfl_xor(S, mk);
        const float Mn = fmaxf(M, Mo);
        S = S * __expf(M - Mn) + So * __expf(Mo - Mn);
        M = Mn;
    }
    if (tcol == 0)
        lse[row] = M + logf(S);
}

__global__ __launch_bounds__(256)
void k4_final(const float* __restrict__ lse, const float* __restrict__ pos,
              float* __restrict__ out)
{
    __shared__ float2 red[256];
    const int tid = threadIdx.x;
    float lacc = 0.f, pacc = 0.f;
    #pragma unroll
    for (int g = 0; g < 4; ++g) {
        const int row = tid + g * 256;
        lacc += lse[row];
        pacc += pos[row];
    }
    red[tid] = make_float2(lacc, pacc);
    __syncthreads();
    for (int s = 128; s > 0; s >>= 1) {
        if (tid < s) {
            float2 o = red[tid + s], m2 = red[tid];
            m2.x += o.x; m2.y += o.y;
            red[tid] = m2;
        }
        __syncthreads();
    }
    if (tid == 0)
        out[0] = red[0].x / (float)NN - logf((float)NN) - red[0].y / (float)NN;
}

extern "C" void kernel_launch(void* const* d_in, const int* in_sizes, int n_in,
                              void* d_out, int out_size, void* d_ws, size_t ws_size,
                              hipStream_t stream)
{
    const float* x  = (const float*)d_in[0];
    const float* y  = (const float*)d_in[1];
    const float* W1 = (const float*)d_in[2];
    const float* b1 = (const float*)d_in[3];
    const float* w2 = (const float*)d_in[4];
    const float* b2 = (const float*)d_in[5];
    float* out = (float*)d_out;

    float* ws     = (float*)d_ws;
    float* xpbT   = ws;                          // 256*1024
    float* ypT    = xpbT + HH * NN;              // 256*1024
    float* pscore = ypT + HH * NN;               // 4*1024*1024
    float* lse    = pscore + (size_t)NKC * NN * NN;
    float* pos    = lse + NN;

    hipLaunchKernelGGL(k1_proj, dim3(NN / 2), dim3(256), 0, stream,
                       x, y, W1, b1, xpbT, ypT);
    hipLaunchKernelGGL(k2_scores, dim3(16, 16, NKC), dim3(256), 0, stream,
                       xpbT, ypT, w2, pscore);
    hipLaunchKernelGGL(k3_lse, dim3(NN / 8), dim3(256), 0, stream,
                       pscore, b2, lse, pos);
    hipLaunchKernelGGL(k4_final, dim3(1), dim3(256), 0, stream,
                       lse, pos, out);
}

// Round 5
// 43.104 us; speedup vs baseline: 1.2171x; 1.1221x over previous
//
#include <hip/hip_runtime.h>
#include <math.h>

#define NN 1024
#define DD 64
#define HH 256
#define TEMP_INV 10.0f
#define KCH 64
#define LPAD 34   // LDS row pad: 34 floats -> 2-way max on write (free), aligned float2

// ws layout (floats):
//   xpbT [HH][NN]  : xp + b1, transposed (k-major)  1 MB
//   ypT  [HH][NN]  : yp, transposed                 1 MB
//   pmax [32][NN]  : per (j-chunk, row) partial max
//   psum [32][NN]  : per (j-chunk, row) partial sum(exp)
//   pos  [NN]

__global__ __launch_bounds__(256)
void k1_proj(const float* __restrict__ x, const float* __restrict__ y,
             const float* __restrict__ W1, const float* __restrict__ b1,
             float* __restrict__ xpbT, float* __restrict__ ypT)
{
    const int tid = threadIdx.x;        // h index 0..255
    const int i0 = blockIdx.x * 2;      // 2 rows per block -> 512 blocks
    float ax0 = 0.f, ax1 = 0.f, ay0 = 0.f, ay1 = 0.f;
    #pragma unroll 8
    for (int kk = 0; kk < DD; ++kk) {
        const float wx = W1[kk * HH + tid];
        const float wy = W1[(DD + kk) * HH + tid];
        ax0 = fmaf(x[i0 * DD + kk],       wx, ax0);
        ax1 = fmaf(x[(i0 + 1) * DD + kk], wx, ax1);
        ay0 = fmaf(y[i0 * DD + kk],       wy, ay0);
        ay1 = fmaf(y[(i0 + 1) * DD + kk], wy, ay1);
    }
    const float b1t = b1[tid];
    *(float2*)&xpbT[tid * NN + i0] = make_float2(ax0 + b1t, ax1 + b1t);
    *(float2*)&ypT[tid * NN + i0]  = make_float2(ay0, ay1);
}

// 32x32 output tile, FULL K per block, 2x2 register tile per thread.
// Grid 32x32 = 1024 blocks x 4 waves = 4 waves/SIMD. Partial LSE in-block.
__global__ __launch_bounds__(256, 4)
void k2_scores(const float* __restrict__ xpbT, const float* __restrict__ ypT,
               const float* __restrict__ w2, const float* __restrict__ b2,
               float* __restrict__ pmax, float* __restrict__ psum,
               float* __restrict__ pos)
{
    __shared__ float ys[KCH][LPAD];   // ~8.7 KB
    __shared__ float xs[KCH][LPAD];   // ~8.7 KB
    const int tid = threadIdx.x;
    const int jc = blockIdx.x, ic = blockIdx.y;
    const int i0 = ic * 32, j0 = jc * 32;
    const int lr = tid >> 4;          // 0..15 -> rows 2lr, 2lr+1
    const int lc = tid & 15;          // 0..15 -> cols 2lc, 2lc+1

    float a00 = 0.f, a01 = 0.f, a10 = 0.f, a11 = 0.f;

    for (int k0 = 0; k0 < HH; k0 += KCH) {
        __syncthreads();
        {   // stage chunk: 128 threads -> ys, 128 -> xs; 2 threads/row x 16 floats
            const int u    = tid & 127;
            const int row  = u >> 1;            // 0..63
            const int half = (u & 1) * 16;      // 0 | 16
            const float* src = (tid >> 7) ? xpbT : ypT;
            const int    bas = (tid >> 7) ? j0 : i0;
            float* dst = (tid >> 7) ? &xs[row][half] : &ys[row][half];
            const float4 v0 = *(const float4*)&src[(k0 + row) * NN + bas + half + 0];
            const float4 v1 = *(const float4*)&src[(k0 + row) * NN + bas + half + 4];
            const float4 v2 = *(const float4*)&src[(k0 + row) * NN + bas + half + 8];
            const float4 v3 = *(const float4*)&src[(k0 + row) * NN + bas + half + 12];
            *(float2*)&dst[0]  = make_float2(v0.x, v0.y);
            *(float2*)&dst[2]  = make_float2(v0.z, v0.w);
            *(float2*)&dst[4]  = make_float2(v1.x, v1.y);
            *(float2*)&dst[6]  = make_float2(v1.z, v1.w);
            *(float2*)&dst[8]  = make_float2(v2.x, v2.y);
            *(float2*)&dst[10] = make_float2(v2.z, v2.w);
            *(float2*)&dst[12] = make_float2(v3.x, v3.y);
            *(float2*)&dst[14] = make_float2(v3.z, v3.w);
        }
        __syncthreads();

        #pragma unroll 8
        for (int kk = 0; kk < KCH; ++kk) {
            const float w2k = w2[k0 + kk];                    // uniform -> s_load
            const float2 yv = *(const float2*)&ys[kk][lr * 2];
            const float2 xv = *(const float2*)&xs[kk][lc * 2];
            a00 = fmaf(fmaxf(yv.x + xv.x, 0.f), w2k, a00);
            a01 = fmaf(fmaxf(yv.x + xv.y, 0.f), w2k, a01);
            a10 = fmaf(fmaxf(yv.y + xv.x, 0.f), w2k, a10);
            a11 = fmaf(fmaxf(yv.y + xv.y, 0.f), w2k, a11);
        }
    }

    const float bb = b2[0];
    const float s00 = (a00 + bb) * TEMP_INV;
    const float s01 = (a01 + bb) * TEMP_INV;
    const float s10 = (a10 + bb) * TEMP_INV;
    const float s11 = (a11 + bb) * TEMP_INV;

    // diagonal (pos): needs ic==jc, lr==lc, r==c
    if (ic == jc && lr == lc) {
        pos[i0 + lr * 2]     = s00;
        pos[i0 + lr * 2 + 1] = s11;
    }

    // per-row partial (max, sum-exp) over this block's 32 cols.
    // lane = (lr&3)*16 + lc; xor masks 1,2,4,8 reduce over lc only.
    float m0 = fmaxf(s00, s01);
    float e0 = __expf(s00 - m0) + __expf(s01 - m0);
    float m1 = fmaxf(s10, s11);
    float e1 = __expf(s10 - m1) + __expf(s11 - m1);
    #pragma unroll
    for (int mk = 8; mk >= 1; mk >>= 1) {
        const float m0o = __shfl_xor(m0, mk), e0o = __shfl_xor(e0, mk);
        const float m1o = __shfl_xor(m1, mk), e1o = __shfl_xor(e1, mk);
        float mn = fmaxf(m0, m0o);
        e0 = e0 * __expf(m0 - mn) + e0o * __expf(m0o - mn); m0 = mn;
        mn = fmaxf(m1, m1o);
        e1 = e1 * __expf(m1 - mn) + e1o * __expf(m1o - mn); m1 = mn;
    }
    if (lc == 0) {
        const int r0 = i0 + lr * 2;
        pmax[jc * NN + r0]     = m0;
        psum[jc * NN + r0]     = e0;
        pmax[jc * NN + r0 + 1] = m1;
        psum[jc * NN + r0 + 1] = e1;
    }
}

// Single block, 1024 threads: one row per thread. Combine 32 partials,
// add pos, block-reduce, write the scalar. No atomics.
__global__ __launch_bounds__(1024)
void k3_final(const float* __restrict__ pmax, const float* __restrict__ psum,
              const float* __restrict__ pos, float* __restrict__ out)
{
    __shared__ float2 red[1024];
    const int tid = threadIdx.x;      // row
    float M = pmax[tid], E = psum[tid];
    #pragma unroll 8
    for (int jc = 1; jc < 32; ++jc) {
        const float Mo = pmax[jc * NN + tid];
        const float Eo = psum[jc * NN + tid];
        const float Mn = fmaxf(M, Mo);
        E = E * __expf(M - Mn) + Eo * __expf(Mo - Mn);
        M = Mn;
    }
    red[tid] = make_float2(M + logf(E), pos[tid]);
    __syncthreads();
    for (int s = 512; s > 0; s >>= 1) {
        if (tid < s) {
            const float2 o = red[tid + s];
            float2 m2 = red[tid];
            m2.x += o.x; m2.y += o.y;
            red[tid] = m2;
        }
        __syncthreads();
    }
    if (tid == 0)
        out[0] = red[0].x / (float)NN - logf((float)NN) - red[0].y / (float)NN;
}

extern "C" void kernel_launch(void* const* d_in, const int* in_sizes, int n_in,
                              void* d_out, int out_size, void* d_ws, size_t ws_size,
                              hipStream_t stream)
{
    const float* x  = (const float*)d_in[0];
    const float* y  = (const float*)d_in[1];
    const float* W1 = (const float*)d_in[2];
    const float* b1 = (const float*)d_in[3];
    const float* w2 = (const float*)d_in[4];
    const float* b2 = (const float*)d_in[5];
    float* out = (float*)d_out;

    float* ws   = (float*)d_ws;
    float* xpbT = ws;                 // 256*1024
    float* ypT  = xpbT + HH * NN;     // 256*1024
    float* pmax = ypT + HH * NN;      // 32*1024
    float* psum = pmax + 32 * NN;     // 32*1024
    float* pos  = psum + 32 * NN;     // 1024

    hipLaunchKernelGGL(k1_proj, dim3(NN / 2), dim3(256), 0, stream,
                       x, y, W1, b1, xpbT, ypT);
    hipLaunchKernelGGL(k2_scores, dim3(32, 32), dim3(256), 0, stream,
                       xpbT, ypT, w2, b2, pmax, psum, pos);
    hipLaunchKernelGGL(k3_final, dim3(1), dim3(1024), 0, stream,
                       pmax, psum, pos, out);
}